// Round 7
// baseline (321.320 us; speedup 1.0000x reference)
//
#include <hip/hip_runtime.h>
#include <hip/hip_bf16.h>
#include <cstdint>

typedef unsigned short u16;
typedef __attribute__((ext_vector_type(8))) short bf16x8;
typedef __attribute__((ext_vector_type(4))) float f32x4;

__device__ __forceinline__ u16 f2b(float f) {
  union { float f; unsigned u; } x; x.f = f;
  unsigned r = x.u + 0x7fffu + ((x.u >> 16) & 1u);   // RNE
  return (u16)(r >> 16);
}
__device__ __forceinline__ float b2f(u16 u) {
  union { unsigned u; float f; } x; x.u = ((unsigned)u) << 16;
  return x.f;
}
__device__ __forceinline__ void gld16(void* lds, const void* g) {
  __builtin_amdgcn_global_load_lds((const __attribute__((address_space(1))) void*)g,
                                   (__attribute__((address_space(3))) void*)lds, 16, 0, 0);
}
__device__ __forceinline__ int sw_idx(int n, int c) {
  return n * 64 + ((((c >> 2) ^ (n >> 2)) & 15) << 2) + (c & 3);
}
// Ek/Vs swizzle: bijective per row; conflict-free for both the scalar b16
// epilogue writes and the 16B fragment reads.
__device__ __forceinline__ int ekb(int row, int c2) {
  return (row * 256 + c2) ^ ((((row >> 3) ^ row) & 7) << 4);
}

// ---------------------------------------------------------------------------
// pre: fused preprocessing (one launch).
//  blk<4096    : xt path — transpose-convert x [b][512][4096] fp32 ->
//                xt [b][4096][512] bf16 (64x64 tiles via swizzled LDS)
//  blk<4608    : convert w_qkv rows 512..1535 -> wkvh bf16, HEAD-MAJOR:
//                wkvh[h*128+d] = k-ch h*64+d; wkvh[h*128+64+e] = v-ch h*64+e
//  blk<4672    : transpose-convert w_qkv rows 0..511 -> wqT bf16 [i][ch]
//  else        : zero ctx+rsum (266240 floats)
// ---------------------------------------------------------------------------
__global__ __launch_bounds__(256) void pre(const float* __restrict__ x,
                                           u16* __restrict__ xt,
                                           const float* __restrict__ w_qkv,
                                           u16* __restrict__ wkvh,
                                           u16* __restrict__ wqT,
                                           float* __restrict__ zbuf) {
  __shared__ u16 t[4096];
  const int tid = threadIdx.x;
  const int blk = blockIdx.x;
  if (blk < 4096) {
    const int b = blk >> 9;
    const int c0 = ((blk >> 6) & 7) * 64;
    const int n0 = (blk & 63) * 64;
    const int nl = (tid & 15) * 4;
    const int cl = tid >> 4;
#pragma unroll
    for (int r = 0; r < 4; r++) {
      const int c = cl + r * 16;
      const float4 v = *(const float4*)(x + ((long)b * 512 + c0 + c) * 4096 + n0 + nl);
      t[sw_idx(nl + 0, c)] = f2b(v.x);
      t[sw_idx(nl + 1, c)] = f2b(v.y);
      t[sw_idx(nl + 2, c)] = f2b(v.z);
      t[sw_idx(nl + 3, c)] = f2b(v.w);
    }
    __syncthreads();
    const int cw = (tid & 15) * 4;
#pragma unroll
    for (int r = 0; r < 4; r++) {
      const int n = cl + r * 16;
      const u16* tp = &t[sw_idx(n, cw)];
      ushort4 o; o.x = tp[0]; o.y = tp[1]; o.z = tp[2]; o.w = tp[3];
      *(ushort4*)(xt + ((long)b * 4096 + n0 + n) * 512 + c0 + cw) = o;
    }
    return;
  }
  const int pblk = blk - 4096;
  if (pblk < 512) {
    const int i = pblk * 1024 + tid * 4;
    const int ri = i >> 9;          // 0..1023 (0..511 = k, 512..1023 = v)
    const int col = i & 511;
    const int h = (ri >> 6) & 7;
    const int orow = h * 128 + ((ri >> 9) << 6) + (ri & 63);
    const float4 v = *(const float4*)(w_qkv + 262144 + i);
    ushort4 r; r.x = f2b(v.x); r.y = f2b(v.y); r.z = f2b(v.z); r.w = f2b(v.w);
    *(ushort4*)(wkvh + orow * 512 + col) = r;
  } else if (pblk < 576) {
    const int bb = pblk - 512;
    const int i0 = (bb & 7) * 64;
    const int c0 = (bb >> 3) * 64;
    const int il = (tid & 15) * 4;
    const int cl = tid >> 4;
#pragma unroll
    for (int r = 0; r < 4; r++) {
      const int c = cl + r * 16;
      const float4 v = *(const float4*)(w_qkv + (c0 + c) * 512 + i0 + il);
      t[sw_idx(il + 0, c)] = f2b(v.x);
      t[sw_idx(il + 1, c)] = f2b(v.y);
      t[sw_idx(il + 2, c)] = f2b(v.z);
      t[sw_idx(il + 3, c)] = f2b(v.w);
    }
    __syncthreads();
    const int cw = (tid & 15) * 4;
#pragma unroll
    for (int r = 0; r < 4; r++) {
      const int i = cl + r * 16;
      const u16* tp = &t[sw_idx(i, cw)];
      ushort4 o; o.x = tp[0]; o.y = tp[1]; o.z = tp[2]; o.w = tp[3];
      *(ushort4*)(wqT + (i0 + i) * 512 + c0 + cw) = o;
    }
  } else {
    const int zi = (pblk - 576) * 1024 + tid * 4;
    if (zi < 266240) *(float4*)(zbuf + zi) = float4{0.f, 0.f, 0.f, 0.f};
  }
}

// ---------------------------------------------------------------------------
// kvctx: fused kv_gemm + ctx_gemm. One block = (head h, 128-n chunk, b).
// GEMM1: BK=64 m97 variant (R4-verified schedule). As/Bs [128][64] bf16 with
// 16B-chunk XOR swizzle (chunk ^= row&7): gld16 dest linear, GLOBAL source
// chunk pre-swizzled, fragment reads apply the same XOR (rule 21) ->
// 2 lanes/bank (free). Epilogue: exp k-half, rsum reduce+atomic, swizzled
// Ek/Vs LDS round-trip (aliases As/Bs), ctx MFMA over n (K=128), fp32
// atomics into ctx.
// XCD-aware flat grid (2048): all 8 heads of one (nc,b) xt tile on the
// SAME XCD consecutively -> B-tile fetched once per XCD L2.
// launch_bounds(256,5): LDS 32KB and VGPR(64)<=102 both permit 5 blocks/CU.
// ---------------------------------------------------------------------------
__global__ __launch_bounds__(256, 5) void kvctx(const u16* __restrict__ wkvh,
                                                const u16* __restrict__ xt,
                                                float* __restrict__ ctx,
                                                float* __restrict__ rsum) {
  __shared__ u16 sh[16384];      // 32 KB total
  u16* As = sh;                  // [128][64] 16 KB   (GEMM1 phase)
  u16* Bs = sh + 8192;           // [128][64] 16 KB   (GEMM1 phase)
  u16* Ek = sh;                  // [64][128] 16 KB   (aliases As, ctx phase)
  u16* Vs = sh + 8192;           // [64][128] 16 KB   (aliases Bs, ctx phase)

  const int tid = threadIdx.x;
  const int wid = tid >> 6;
  const int lane = tid & 63;
  const int wm = wid >> 1, wn = wid & 1;

  // XCD-chunked work decode: 256 tiles (32 nc x 8 b), 8 heads each.
  const int flat = blockIdx.x;
  const int xcd = flat & 7;
  const int slot = flat >> 3;          // 0..255 per XCD
  const int h = slot & 7;
  const int tile = xcd * 32 + (slot >> 3);   // 0..255
  const int nc = tile & 31;
  const int b = tile >> 5;
  const int bh = b * 8 + h;

  const u16* Ab = wkvh + (long)h * 128 * 512;
  const u16* Bb = xt + ((long)b * 4096 + (long)nc * 128) * 512;
  const int q8 = (lane >> 4) * 8;
  const int mr = lane & 15;
  const int quad = lane >> 4;
  const int m7 = mr & 7;

  f32x4 acc[4][4] = {};

  // staging decode (per gld16 slot): row 0..127, chunk 0..7, swizzled source
  for (int kk = 0; kk < 512; kk += 64) {
    __syncthreads();
#pragma unroll
    for (int i = 0; i < 4; i++) {
      const int slot2 = i * 256 + tid;           // 0..1023
      const int row = slot2 >> 3;
      const int kc = ((slot2 & 7) ^ (row & 7)) * 8;   // pre-swizzled source
      gld16((char*)As + i * 4096 + wid * 1024, Ab + (long)row * 512 + kk + kc);
      gld16((char*)Bs + i * 4096 + wid * 1024, Bb + (long)row * 512 + kk + kc);
    }
    __syncthreads();
#pragma unroll
    for (int ks = 0; ks < 2; ks++) {
      bf16x8 af[4], bfv[4];
#pragma unroll
      for (int i = 0; i < 4; i++)
        af[i] = *(const bf16x8*)(As + (wm * 64 + i * 16 + mr) * 64 +
                                 (((ks * 4 + quad) ^ m7) * 8));
#pragma unroll
      for (int j = 0; j < 4; j++)
        bfv[j] = *(const bf16x8*)(Bs + (wn * 64 + j * 16 + mr) * 64 +
                                  (((ks * 4 + quad) ^ m7) * 8));
#pragma unroll
      for (int i = 0; i < 4; i++)
#pragma unroll
        for (int j = 0; j < 4; j++)
          acc[i][j] = __builtin_amdgcn_mfma_f32_16x16x32_bf16(af[i], bfv[j], acc[i][j], 0, 0, 0);
    }
  }

  // ---- epilogue: exp k-half, rsum, write swizzled LDS tiles ----
  __syncthreads();   // everyone done reading As/Bs before Ek overwrites them
  u16* dst = (wm == 0) ? Ek : Vs;   // wm=0 waves hold k rows 0..63, wm=1 v rows
#pragma unroll
  for (int i = 0; i < 4; i++) {
#pragma unroll
    for (int r = 0; r < 4; r++) {
      const int row = i * 16 + quad * 4 + r;   // 0..63 within half
      float sloc = 0.f;
#pragma unroll
      for (int j = 0; j < 4; j++) {
        float v = acc[i][j][r];
        if (wm == 0) v = __expf(v);
        const u16 bv = f2b(v);
        const int col = wn * 64 + j * 16 + mr;
        *(u16*)((char*)dst + ekb(row, col * 2)) = bv;
        if (wm == 0) sloc += b2f(bv);   // sum the rounded value for consistency
      }
      if (wm == 0) {
        sloc += __shfl_xor(sloc, 1);
        sloc += __shfl_xor(sloc, 2);
        sloc += __shfl_xor(sloc, 4);
        sloc += __shfl_xor(sloc, 8);
        if (mr == 0) atomicAdd(rsum + (long)bh * 64 + row, sloc);
      }
    }
  }
  __syncthreads();

  // ---- ctx MFMA: K = 128 n of this tile ----
  f32x4 acc2[2][2] = {};
#pragma unroll
  for (int ks = 0; ks < 4; ks++) {
    bf16x8 ef[2], vf[2];
#pragma unroll
    for (int ii = 0; ii < 2; ii++) {
      const int row = wm * 32 + ii * 16 + mr;          // d
      ef[ii] = *(const bf16x8*)((const char*)Ek + ekb(row, (ks * 32 + q8) * 2));
    }
#pragma unroll
    for (int jj = 0; jj < 2; jj++) {
      const int row = wn * 32 + jj * 16 + mr;          // e
      vf[jj] = *(const bf16x8*)((const char*)Vs + ekb(row, (ks * 32 + q8) * 2));
    }
#pragma unroll
    for (int ii = 0; ii < 2; ii++)
#pragma unroll
      for (int jj = 0; jj < 2; jj++)
        acc2[ii][jj] = __builtin_amdgcn_mfma_f32_16x16x32_bf16(ef[ii], vf[jj], acc2[ii][jj], 0, 0, 0);
  }

  // ---- ctx atomics ----
  float* cb = ctx + (long)bh * 4096;
#pragma unroll
  for (int ii = 0; ii < 2; ii++)
#pragma unroll
    for (int jj = 0; jj < 2; jj++)
#pragma unroll
      for (int r = 0; r < 4; r++) {
        const int d = wm * 32 + ii * 16 + quad * 4 + r;
        const int e = wn * 32 + jj * 16 + mr;
        atomicAdd(cb + d * 64 + e, acc2[ii][jj][r]);
      }
}

// ---------------------------------------------------------------------------
// Wc[b][o][h*64+d] = (sum_e w_out[o][h*64+e] * ctx[bh][d][e]) / rsum[bh*64+d]
// ---------------------------------------------------------------------------
__global__ __launch_bounds__(256) void wc_kern(const float* __restrict__ ctxp,
                                               const float* __restrict__ rsump,
                                               const float* __restrict__ wout,
                                               u16* __restrict__ Wc) {
  __shared__ float cs[64 * 65];
  const int tid = threadIdx.x;
  const int bh = blockIdx.x, og = blockIdx.y;
  const int b = bh >> 3, h = bh & 7;
  for (int i = tid; i < 4096; i += 256) {
    const int d = i >> 6, e = i & 63;
    cs[e * 65 + d] = ctxp[(long)bh * 4096 + i] / rsump[(long)bh * 64 + d];
  }
  __syncthreads();
  const int d = tid & 63;
  const int o0 = og * 128 + (tid >> 6) * 32;
  float csr[64];
#pragma unroll
  for (int e = 0; e < 64; e++) csr[e] = cs[e * 65 + d];
  u16* wcp = Wc + (long)b * 512 * 512;
  for (int rr = 0; rr < 32; rr++) {
    const int o = o0 + rr;
    const float* wrow = wout + (long)o * 512 + h * 64;
    float a0 = 0.f, a1 = 0.f, a2 = 0.f, a3 = 0.f;
#pragma unroll
    for (int e = 0; e < 64; e += 4) {
      a0 += wrow[e + 0] * csr[e + 0];
      a1 += wrow[e + 1] * csr[e + 1];
      a2 += wrow[e + 2] * csr[e + 2];
      a3 += wrow[e + 3] * csr[e + 3];
    }
    wcp[(long)o * 512 + h * 64 + d] = f2b((a0 + a1) + (a2 + a3));
  }
}

// ---------------------------------------------------------------------------
// Weff[b][o][i] = 0.125 * sum_ch Wc[b][o][ch] * wqT[i][ch].  grid (4, 4, 8).
// ---------------------------------------------------------------------------
__global__ __launch_bounds__(256) void weff_gemm(const u16* __restrict__ Wc,
                                                 const u16* __restrict__ wqT,
                                                 u16* __restrict__ Weff) {
  __shared__ u16 As[128 * 32];
  __shared__ u16 Bs[128 * 32];
  const int tid = threadIdx.x;
  const int wid = tid >> 6;
  const int lane = tid & 63;
  const int wm = wid >> 1, wn = wid & 1;
  const int gn = blockIdx.x, gm = blockIdx.y, b = blockIdx.z;

  const u16* Ab = Wc + (long)b * 512 * 512 + (long)gm * 128 * 512;
  const u16* Bb = wqT + (long)gn * 128 * 512;

  f32x4 acc[4][4] = {};
  const int q8 = (lane >> 4) * 8;
  const int mr = lane & 15;

  for (int kk = 0; kk < 512; kk += 32) {
    __syncthreads();
#pragma unroll
    for (int i = 0; i < 2; i++) {
      const int slot = i * 256 + tid;
      const int row = slot >> 2;
      const int kc = (slot & 3) * 8;
      gld16((char*)As + i * 4096 + wid * 1024, Ab + (long)row * 512 + kk + kc);
      gld16((char*)Bs + i * 4096 + wid * 1024, Bb + (long)row * 512 + kk + kc);
    }
    __syncthreads();
    bf16x8 af[4], bfv[4];
#pragma unroll
    for (int i = 0; i < 4; i++)
      af[i] = *(const bf16x8*)(As + (wm * 64 + i * 16 + mr) * 32 + q8);
#pragma unroll
    for (int j = 0; j < 4; j++)
      bfv[j] = *(const bf16x8*)(Bs + (wn * 64 + j * 16 + mr) * 32 + q8);
#pragma unroll
    for (int i = 0; i < 4; i++)
#pragma unroll
      for (int j = 0; j < 4; j++)
        acc[i][j] = __builtin_amdgcn_mfma_f32_16x16x32_bf16(af[i], bfv[j], acc[i][j], 0, 0, 0);
  }

  const int col = lane & 15;
  const int quad = lane >> 4;
  u16* wb = Weff + (long)b * 512 * 512;
#pragma unroll
  for (int i = 0; i < 4; i++)
#pragma unroll
    for (int r = 0; r < 4; r++) {
      const int grow = gm * 128 + wm * 64 + i * 16 + quad * 4 + r;
#pragma unroll
      for (int j = 0; j < 4; j++) {
        const int gcol = gn * 128 + wn * 64 + j * 16 + col;
        wb[(long)grow * 512 + gcol] = f2b(acc[i][j][r] * 0.125f);
      }
    }
}

// ---------------------------------------------------------------------------
// out_gemm: out[b][o][n] = sum_i Weff[b][o][i] * xt[b][n][i] + bias[o]
// BK=64 + chunk-XOR swizzle (same scheme as kvctx GEMM1, R4-verified).
// grid (32, 4, 8): gn fastest keeps the 4 gm-sharers of one xt B-tile on
// the same XCD. launch_bounds(256,5): 5 blocks/CU by LDS and VGPR.
// ---------------------------------------------------------------------------
__global__ __launch_bounds__(256, 5) void out_gemm(const u16* __restrict__ Weff,
                                                   const u16* __restrict__ xt,
                                                   const float* __restrict__ bias,
                                                   float* __restrict__ outp) {
  __shared__ u16 As[128 * 64];
  __shared__ u16 Bs[128 * 64];
  const int tid = threadIdx.x;
  const int wid = tid >> 6;
  const int lane = tid & 63;
  const int wm = wid >> 1, wn = wid & 1;
  const int gn = blockIdx.x, gm = blockIdx.y, b = blockIdx.z;

  const u16* Ab = Weff + (long)b * 512 * 512 + (long)gm * 128 * 512;
  const u16* Bb = xt + ((long)b * 4096 + (long)gn * 128) * 512;

  f32x4 acc[4][4] = {};
  const int mr = lane & 15;
  const int quad = lane >> 4;
  const int m7 = mr & 7;

  for (int kk = 0; kk < 512; kk += 64) {
    __syncthreads();
#pragma unroll
    for (int i = 0; i < 4; i++) {
      const int slot = i * 256 + tid;
      const int row = slot >> 3;
      const int kc = ((slot & 7) ^ (row & 7)) * 8;
      gld16((char*)As + i * 4096 + wid * 1024, Ab + (long)row * 512 + kk + kc);
      gld16((char*)Bs + i * 4096 + wid * 1024, Bb + (long)row * 512 + kk + kc);
    }
    __syncthreads();
#pragma unroll
    for (int ks = 0; ks < 2; ks++) {
      bf16x8 af[4], bfv[4];
#pragma unroll
      for (int i = 0; i < 4; i++)
        af[i] = *(const bf16x8*)(As + (wm * 64 + i * 16 + mr) * 64 +
                                 (((ks * 4 + quad) ^ m7) * 8));
#pragma unroll
      for (int j = 0; j < 4; j++)
        bfv[j] = *(const bf16x8*)(Bs + (wn * 64 + j * 16 + mr) * 64 +
                                  (((ks * 4 + quad) ^ m7) * 8));
#pragma unroll
      for (int i = 0; i < 4; i++)
#pragma unroll
        for (int j = 0; j < 4; j++)
          acc[i][j] = __builtin_amdgcn_mfma_f32_16x16x32_bf16(af[i], bfv[j], acc[i][j], 0, 0, 0);
    }
  }

  const int col = lane & 15;
#pragma unroll
  for (int i = 0; i < 4; i++)
#pragma unroll
    for (int r = 0; r < 4; r++) {
      const int grow = gm * 128 + wm * 64 + i * 16 + quad * 4 + r;
      const float bv = bias[grow];
#pragma unroll
      for (int j = 0; j < 4; j++) {
        const long gcol = (long)gn * 128 + wn * 64 + j * 16 + col;
        outp[((long)b * 512 + grow) * 4096 + gcol] = acc[i][j][r] + bv;
      }
    }
}

// ---------------------------------------------------------------------------
// launcher
// ---------------------------------------------------------------------------
extern "C" void kernel_launch(void* const* d_in, const int* in_sizes, int n_in,
                              void* d_out, int out_size, void* d_ws, size_t ws_size,
                              hipStream_t stream) {
  const float* x = (const float*)d_in[0];      // [8][512][4096]
  const float* w_qkv = (const float*)d_in[1];  // [1536][512]
  const float* w_out = (const float*)d_in[2];  // [512][512]
  const float* b_out = (const float*)d_in[3];  // [512]
  float* out = (float*)d_out;                  // [8][512][4096]
  char* ws = (char*)d_ws;

  u16* xt = (u16*)(ws + 0);                    // 32 MB  [b][n][512] bf16
  u16* wkvh = (u16*)(ws + 33554432);           //  1 MB  head-major Wkv bf16
  u16* wqT = (u16*)(ws + 34603008);            // .5 MB  Wq^T bf16 [i][ch]
  u16* wc = (u16*)(ws + 35127296);             //  4 MB  Wc bf16 [b][o][ch]
  u16* weff = (u16*)(ws + 39321600);           //  4 MB  Weff bf16 [b][o][i]
  float* ctx = (float*)(ws + 43515904);        //  1 MB  [bh][d][e] fp32 (atomic)
  float* rsum = (float*)(ws + 44564480);       // 16 KB  [bh*64+d]   fp32 (atomic)

  pre<<<4932, 256, 0, stream>>>(x, xt, w_qkv, wkvh, wqT, ctx);
  kvctx<<<2048, 256, 0, stream>>>(wkvh, xt, ctx, rsum);
  wc_kern<<<dim3(64, 4), 256, 0, stream>>>(ctx, rsum, w_out, wc);
  weff_gemm<<<dim3(4, 4, 8), 256, 0, stream>>>(wc, wqT, weff);
  out_gemm<<<dim3(32, 4, 8), 256, 0, stream>>>(weff, xt, b_out, out);
}

// Round 8
// 253.746 us; speedup vs baseline: 1.2663x; 1.2663x over previous
//
#include <hip/hip_runtime.h>
#include <hip/hip_bf16.h>
#include <cstdint>

typedef unsigned short u16;
typedef __attribute__((ext_vector_type(8))) short bf16x8;
typedef __attribute__((ext_vector_type(4))) float f32x4;

__device__ __forceinline__ u16 f2b(float f) {
  union { float f; unsigned u; } x; x.f = f;
  unsigned r = x.u + 0x7fffu + ((x.u >> 16) & 1u);   // RNE
  return (u16)(r >> 16);
}
__device__ __forceinline__ float b2f(u16 u) {
  union { unsigned u; float f; } x; x.u = ((unsigned)u) << 16;
  return x.f;
}
__device__ __forceinline__ void gld16(void* lds, const void* g) {
  __builtin_amdgcn_global_load_lds((const __attribute__((address_space(1))) void*)g,
                                   (__attribute__((address_space(3))) void*)lds, 16, 0, 0);
}
__device__ __forceinline__ int sw_idx(int n, int c) {
  return n * 64 + ((((c >> 2) ^ (n >> 2)) & 15) << 2) + (c & 3);
}
// Ek/Vs swizzle: bijective per row; conflict-free for both the scalar b16
// epilogue writes and the 16B fragment reads.
__device__ __forceinline__ int ekb(int row, int c2) {
  return (row * 256 + c2) ^ ((((row >> 3) ^ row) & 7) << 4);
}

// ---------------------------------------------------------------------------
// pre: fused preprocessing (one launch).
//  blk<4096    : xt path — transpose-convert x [b][512][4096] fp32 ->
//                xt [b][4096][512] bf16 (64x64 tiles via swizzled LDS)
//  blk<4608    : convert w_qkv rows 512..1535 -> wkvh bf16, HEAD-MAJOR:
//                wkvh[h*128+d] = k-ch h*64+d; wkvh[h*128+64+e] = v-ch h*64+e
//  blk<4672    : transpose-convert w_qkv rows 0..511 -> wqT bf16 [i][ch]
//  else        : zero ctx+rsum (266240 floats)
// ---------------------------------------------------------------------------
__global__ __launch_bounds__(256) void pre(const float* __restrict__ x,
                                           u16* __restrict__ xt,
                                           const float* __restrict__ w_qkv,
                                           u16* __restrict__ wkvh,
                                           u16* __restrict__ wqT,
                                           float* __restrict__ zbuf) {
  __shared__ u16 t[4096];
  const int tid = threadIdx.x;
  const int blk = blockIdx.x;
  if (blk < 4096) {
    const int b = blk >> 9;
    const int c0 = ((blk >> 6) & 7) * 64;
    const int n0 = (blk & 63) * 64;
    const int nl = (tid & 15) * 4;
    const int cl = tid >> 4;
#pragma unroll
    for (int r = 0; r < 4; r++) {
      const int c = cl + r * 16;
      const float4 v = *(const float4*)(x + ((long)b * 512 + c0 + c) * 4096 + n0 + nl);
      t[sw_idx(nl + 0, c)] = f2b(v.x);
      t[sw_idx(nl + 1, c)] = f2b(v.y);
      t[sw_idx(nl + 2, c)] = f2b(v.z);
      t[sw_idx(nl + 3, c)] = f2b(v.w);
    }
    __syncthreads();
    const int cw = (tid & 15) * 4;
#pragma unroll
    for (int r = 0; r < 4; r++) {
      const int n = cl + r * 16;
      const u16* tp = &t[sw_idx(n, cw)];
      ushort4 o; o.x = tp[0]; o.y = tp[1]; o.z = tp[2]; o.w = tp[3];
      *(ushort4*)(xt + ((long)b * 4096 + n0 + n) * 512 + c0 + cw) = o;
    }
    return;
  }
  const int pblk = blk - 4096;
  if (pblk < 512) {
    const int i = pblk * 1024 + tid * 4;
    const int ri = i >> 9;          // 0..1023 (0..511 = k, 512..1023 = v)
    const int col = i & 511;
    const int h = (ri >> 6) & 7;
    const int orow = h * 128 + ((ri >> 9) << 6) + (ri & 63);
    const float4 v = *(const float4*)(w_qkv + 262144 + i);
    ushort4 r; r.x = f2b(v.x); r.y = f2b(v.y); r.z = f2b(v.z); r.w = f2b(v.w);
    *(ushort4*)(wkvh + orow * 512 + col) = r;
  } else if (pblk < 576) {
    const int bb = pblk - 512;
    const int i0 = (bb & 7) * 64;
    const int c0 = (bb >> 3) * 64;
    const int il = (tid & 15) * 4;
    const int cl = tid >> 4;
#pragma unroll
    for (int r = 0; r < 4; r++) {
      const int c = cl + r * 16;
      const float4 v = *(const float4*)(w_qkv + (c0 + c) * 512 + i0 + il);
      t[sw_idx(il + 0, c)] = f2b(v.x);
      t[sw_idx(il + 1, c)] = f2b(v.y);
      t[sw_idx(il + 2, c)] = f2b(v.z);
      t[sw_idx(il + 3, c)] = f2b(v.w);
    }
    __syncthreads();
    const int cw = (tid & 15) * 4;
#pragma unroll
    for (int r = 0; r < 4; r++) {
      const int i = cl + r * 16;
      const u16* tp = &t[sw_idx(i, cw)];
      ushort4 o; o.x = tp[0]; o.y = tp[1]; o.z = tp[2]; o.w = tp[3];
      *(ushort4*)(wqT + (i0 + i) * 512 + c0 + cw) = o;
    }
  } else {
    const int zi = (pblk - 576) * 1024 + tid * 4;
    if (zi < 266240) *(float4*)(zbuf + zi) = float4{0.f, 0.f, 0.f, 0.f};
  }
}

// ---------------------------------------------------------------------------
// kvctx: fused kv_gemm + ctx_gemm. One block = (head h, 128-n chunk, b).
// GEMM1: BK=64 m97 variant (R4-verified schedule, 63.5us). As/Bs [128][64]
// bf16 with 16B-chunk XOR swizzle (chunk ^= row&7): gld16 dest linear,
// GLOBAL source chunk pre-swizzled, fragment reads apply the same XOR
// (rule 21) -> 2 lanes/bank (free). Epilogue: exp k-half, rsum
// reduce+atomic, swizzled Ek/Vs LDS round-trip (aliases As/Bs), ctx MFMA
// over n (K=128), fp32 atomics into ctx.
// XCD-aware flat grid (2048): all 8 heads of one (nc,b) xt tile on the
// SAME XCD consecutively -> B-tile fetched once per XCD L2.
// launch_bounds(256,4): regs (64 VGPR + ~80 acc AGPR on unified file) give
// ~3 blocks/CU; do NOT request more — (256,5) forced spills (R7: +180MB
// scratch traffic, kvctx 63.5->109.7us).
// ---------------------------------------------------------------------------
__global__ __launch_bounds__(256, 4) void kvctx(const u16* __restrict__ wkvh,
                                                const u16* __restrict__ xt,
                                                float* __restrict__ ctx,
                                                float* __restrict__ rsum) {
  __shared__ u16 sh[16384];      // 32 KB total
  u16* As = sh;                  // [128][64] 16 KB   (GEMM1 phase)
  u16* Bs = sh + 8192;           // [128][64] 16 KB   (GEMM1 phase)
  u16* Ek = sh;                  // [64][128] 16 KB   (aliases As, ctx phase)
  u16* Vs = sh + 8192;           // [64][128] 16 KB   (aliases Bs, ctx phase)

  const int tid = threadIdx.x;
  const int wid = tid >> 6;
  const int lane = tid & 63;
  const int wm = wid >> 1, wn = wid & 1;

  // XCD-chunked work decode: 256 tiles (32 nc x 8 b), 8 heads each.
  const int flat = blockIdx.x;
  const int xcd = flat & 7;
  const int slot = flat >> 3;          // 0..255 per XCD
  const int h = slot & 7;
  const int tile = xcd * 32 + (slot >> 3);   // 0..255
  const int nc = tile & 31;
  const int b = tile >> 5;
  const int bh = b * 8 + h;

  const u16* Ab = wkvh + (long)h * 128 * 512;
  const u16* Bb = xt + ((long)b * 4096 + (long)nc * 128) * 512;
  const int q8 = (lane >> 4) * 8;
  const int mr = lane & 15;
  const int quad = lane >> 4;
  const int m7 = mr & 7;

  f32x4 acc[4][4] = {};

  // staging decode (per gld16 slot): row 0..127, chunk 0..7, swizzled source
  for (int kk = 0; kk < 512; kk += 64) {
    __syncthreads();
#pragma unroll
    for (int i = 0; i < 4; i++) {
      const int slot2 = i * 256 + tid;           // 0..1023
      const int row = slot2 >> 3;
      const int kc = ((slot2 & 7) ^ (row & 7)) * 8;   // pre-swizzled source
      gld16((char*)As + i * 4096 + wid * 1024, Ab + (long)row * 512 + kk + kc);
      gld16((char*)Bs + i * 4096 + wid * 1024, Bb + (long)row * 512 + kk + kc);
    }
    __syncthreads();
#pragma unroll
    for (int ks = 0; ks < 2; ks++) {
      bf16x8 af[4], bfv[4];
#pragma unroll
      for (int i = 0; i < 4; i++)
        af[i] = *(const bf16x8*)(As + (wm * 64 + i * 16 + mr) * 64 +
                                 (((ks * 4 + quad) ^ m7) * 8));
#pragma unroll
      for (int j = 0; j < 4; j++)
        bfv[j] = *(const bf16x8*)(Bs + (wn * 64 + j * 16 + mr) * 64 +
                                  (((ks * 4 + quad) ^ m7) * 8));
#pragma unroll
      for (int i = 0; i < 4; i++)
#pragma unroll
        for (int j = 0; j < 4; j++)
          acc[i][j] = __builtin_amdgcn_mfma_f32_16x16x32_bf16(af[i], bfv[j], acc[i][j], 0, 0, 0);
    }
  }

  // ---- epilogue: exp k-half, rsum, write swizzled LDS tiles ----
  __syncthreads();   // everyone done reading As/Bs before Ek overwrites them
  u16* dst = (wm == 0) ? Ek : Vs;   // wm=0 waves hold k rows 0..63, wm=1 v rows
#pragma unroll
  for (int i = 0; i < 4; i++) {
#pragma unroll
    for (int r = 0; r < 4; r++) {
      const int row = i * 16 + quad * 4 + r;   // 0..63 within half
      float sloc = 0.f;
#pragma unroll
      for (int j = 0; j < 4; j++) {
        float v = acc[i][j][r];
        if (wm == 0) v = __expf(v);
        const u16 bv = f2b(v);
        const int col = wn * 64 + j * 16 + mr;
        *(u16*)((char*)dst + ekb(row, col * 2)) = bv;
        if (wm == 0) sloc += b2f(bv);   // sum the rounded value for consistency
      }
      if (wm == 0) {
        sloc += __shfl_xor(sloc, 1);
        sloc += __shfl_xor(sloc, 2);
        sloc += __shfl_xor(sloc, 4);
        sloc += __shfl_xor(sloc, 8);
        if (mr == 0) atomicAdd(rsum + (long)bh * 64 + row, sloc);
      }
    }
  }
  __syncthreads();

  // ---- ctx MFMA: K = 128 n of this tile ----
  f32x4 acc2[2][2] = {};
#pragma unroll
  for (int ks = 0; ks < 4; ks++) {
    bf16x8 ef[2], vf[2];
#pragma unroll
    for (int ii = 0; ii < 2; ii++) {
      const int row = wm * 32 + ii * 16 + mr;          // d
      ef[ii] = *(const bf16x8*)((const char*)Ek + ekb(row, (ks * 32 + q8) * 2));
    }
#pragma unroll
    for (int jj = 0; jj < 2; jj++) {
      const int row = wn * 32 + jj * 16 + mr;          // e
      vf[jj] = *(const bf16x8*)((const char*)Vs + ekb(row, (ks * 32 + q8) * 2));
    }
#pragma unroll
    for (int ii = 0; ii < 2; ii++)
#pragma unroll
      for (int jj = 0; jj < 2; jj++)
        acc2[ii][jj] = __builtin_amdgcn_mfma_f32_16x16x32_bf16(ef[ii], vf[jj], acc2[ii][jj], 0, 0, 0);
  }

  // ---- ctx atomics ----
  float* cb = ctx + (long)bh * 4096;
#pragma unroll
  for (int ii = 0; ii < 2; ii++)
#pragma unroll
    for (int jj = 0; jj < 2; jj++)
#pragma unroll
      for (int r = 0; r < 4; r++) {
        const int d = wm * 32 + ii * 16 + quad * 4 + r;
        const int e = wn * 32 + jj * 16 + mr;
        atomicAdd(cb + d * 64 + e, acc2[ii][jj][r]);
      }
}

// ---------------------------------------------------------------------------
// Wc[b][o][h*64+d] = (sum_e w_out[o][h*64+e] * ctx[bh][d][e]) / rsum[bh*64+d]
// ---------------------------------------------------------------------------
__global__ __launch_bounds__(256) void wc_kern(const float* __restrict__ ctxp,
                                               const float* __restrict__ rsump,
                                               const float* __restrict__ wout,
                                               u16* __restrict__ Wc) {
  __shared__ float cs[64 * 65];
  const int tid = threadIdx.x;
  const int bh = blockIdx.x, og = blockIdx.y;
  const int b = bh >> 3, h = bh & 7;
  for (int i = tid; i < 4096; i += 256) {
    const int d = i >> 6, e = i & 63;
    cs[e * 65 + d] = ctxp[(long)bh * 4096 + i] / rsump[(long)bh * 64 + d];
  }
  __syncthreads();
  const int d = tid & 63;
  const int o0 = og * 128 + (tid >> 6) * 32;
  float csr[64];
#pragma unroll
  for (int e = 0; e < 64; e++) csr[e] = cs[e * 65 + d];
  u16* wcp = Wc + (long)b * 512 * 512;
  for (int rr = 0; rr < 32; rr++) {
    const int o = o0 + rr;
    const float* wrow = wout + (long)o * 512 + h * 64;
    float a0 = 0.f, a1 = 0.f, a2 = 0.f, a3 = 0.f;
#pragma unroll
    for (int e = 0; e < 64; e += 4) {
      a0 += wrow[e + 0] * csr[e + 0];
      a1 += wrow[e + 1] * csr[e + 1];
      a2 += wrow[e + 2] * csr[e + 2];
      a3 += wrow[e + 3] * csr[e + 3];
    }
    wcp[(long)o * 512 + h * 64 + d] = f2b((a0 + a1) + (a2 + a3));
  }
}

// ---------------------------------------------------------------------------
// Weff[b][o][i] = 0.125 * sum_ch Wc[b][o][ch] * wqT[i][ch].  grid (4, 4, 8).
// ---------------------------------------------------------------------------
__global__ __launch_bounds__(256) void weff_gemm(const u16* __restrict__ Wc,
                                                 const u16* __restrict__ wqT,
                                                 u16* __restrict__ Weff) {
  __shared__ u16 As[128 * 32];
  __shared__ u16 Bs[128 * 32];
  const int tid = threadIdx.x;
  const int wid = tid >> 6;
  const int lane = tid & 63;
  const int wm = wid >> 1, wn = wid & 1;
  const int gn = blockIdx.x, gm = blockIdx.y, b = blockIdx.z;

  const u16* Ab = Wc + (long)b * 512 * 512 + (long)gm * 128 * 512;
  const u16* Bb = wqT + (long)gn * 128 * 512;

  f32x4 acc[4][4] = {};
  const int q8 = (lane >> 4) * 8;
  const int mr = lane & 15;

  for (int kk = 0; kk < 512; kk += 32) {
    __syncthreads();
#pragma unroll
    for (int i = 0; i < 2; i++) {
      const int slot = i * 256 + tid;
      const int row = slot >> 2;
      const int kc = (slot & 3) * 8;
      gld16((char*)As + i * 4096 + wid * 1024, Ab + (long)row * 512 + kk + kc);
      gld16((char*)Bs + i * 4096 + wid * 1024, Bb + (long)row * 512 + kk + kc);
    }
    __syncthreads();
    bf16x8 af[4], bfv[4];
#pragma unroll
    for (int i = 0; i < 4; i++)
      af[i] = *(const bf16x8*)(As + (wm * 64 + i * 16 + mr) * 32 + q8);
#pragma unroll
    for (int j = 0; j < 4; j++)
      bfv[j] = *(const bf16x8*)(Bs + (wn * 64 + j * 16 + mr) * 32 + q8);
#pragma unroll
    for (int i = 0; i < 4; i++)
#pragma unroll
      for (int j = 0; j < 4; j++)
        acc[i][j] = __builtin_amdgcn_mfma_f32_16x16x32_bf16(af[i], bfv[j], acc[i][j], 0, 0, 0);
  }

  const int col = lane & 15;
  const int quad = lane >> 4;
  u16* wb = Weff + (long)b * 512 * 512;
#pragma unroll
  for (int i = 0; i < 4; i++)
#pragma unroll
    for (int r = 0; r < 4; r++) {
      const int grow = gm * 128 + wm * 64 + i * 16 + quad * 4 + r;
#pragma unroll
      for (int j = 0; j < 4; j++) {
        const int gcol = gn * 128 + wn * 64 + j * 16 + col;
        wb[(long)grow * 512 + gcol] = f2b(acc[i][j][r] * 0.125f);
      }
    }
}

// ---------------------------------------------------------------------------
// out_gemm: out[b][o][n] = sum_i Weff[b][o][i] * xt[b][n][i] + bias[o]
// BK=64 + chunk-XOR swizzle (R4-verified). grid (32, 4, 8).
// ---------------------------------------------------------------------------
__global__ __launch_bounds__(256) void out_gemm(const u16* __restrict__ Weff,
                                                const u16* __restrict__ xt,
                                                const float* __restrict__ bias,
                                                float* __restrict__ outp) {
  __shared__ u16 As[128 * 64];
  __shared__ u16 Bs[128 * 64];
  const int tid = threadIdx.x;
  const int wid = tid >> 6;
  const int lane = tid & 63;
  const int wm = wid >> 1, wn = wid & 1;
  const int gn = blockIdx.x, gm = blockIdx.y, b = blockIdx.z;

  const u16* Ab = Weff + (long)b * 512 * 512 + (long)gm * 128 * 512;
  const u16* Bb = xt + ((long)b * 4096 + (long)gn * 128) * 512;

  f32x4 acc[4][4] = {};
  const int mr = lane & 15;
  const int quad = lane >> 4;
  const int m7 = mr & 7;

  for (int kk = 0; kk < 512; kk += 64) {
    __syncthreads();
#pragma unroll
    for (int i = 0; i < 4; i++) {
      const int slot = i * 256 + tid;
      const int row = slot >> 3;
      const int kc = ((slot & 7) ^ (row & 7)) * 8;
      gld16((char*)As + i * 4096 + wid * 1024, Ab + (long)row * 512 + kk + kc);
      gld16((char*)Bs + i * 4096 + wid * 1024, Bb + (long)row * 512 + kk + kc);
    }
    __syncthreads();
#pragma unroll
    for (int ks = 0; ks < 2; ks++) {
      bf16x8 af[4], bfv[4];
#pragma unroll
      for (int i = 0; i < 4; i++)
        af[i] = *(const bf16x8*)(As + (wm * 64 + i * 16 + mr) * 64 +
                                 (((ks * 4 + quad) ^ m7) * 8));
#pragma unroll
      for (int j = 0; j < 4; j++)
        bfv[j] = *(const bf16x8*)(Bs + (wn * 64 + j * 16 + mr) * 64 +
                                  (((ks * 4 + quad) ^ m7) * 8));
#pragma unroll
      for (int i = 0; i < 4; i++)
#pragma unroll
        for (int j = 0; j < 4; j++)
          acc[i][j] = __builtin_amdgcn_mfma_f32_16x16x32_bf16(af[i], bfv[j], acc[i][j], 0, 0, 0);
    }
  }

  const int col = lane & 15;
#pragma unroll
  for (int i = 0; i < 4; i++)
#pragma unroll
    for (int r = 0; r < 4; r++) {
      const int grow = gm * 128 + wm * 64 + i * 16 + quad * 4 + r;
      const float bv = bias[grow];
#pragma unroll
      for (int j = 0; j < 4; j++) {
        const long gcol = (long)gn * 128 + wn * 64 + j * 16 + col;
        outp[((long)b * 512 + grow) * 4096 + gcol] = acc[i][j][r] + bv;
      }
    }
}

// ---------------------------------------------------------------------------
// launcher
// ---------------------------------------------------------------------------
extern "C" void kernel_launch(void* const* d_in, const int* in_sizes, int n_in,
                              void* d_out, int out_size, void* d_ws, size_t ws_size,
                              hipStream_t stream) {
  const float* x = (const float*)d_in[0];      // [8][512][4096]
  const float* w_qkv = (const float*)d_in[1];  // [1536][512]
  const float* w_out = (const float*)d_in[2];  // [512][512]
  const float* b_out = (const float*)d_in[3];  // [512]
  float* out = (float*)d_out;                  // [8][512][4096]
  char* ws = (char*)d_ws;

  u16* xt = (u16*)(ws + 0);                    // 32 MB  [b][n][512] bf16
  u16* wkvh = (u16*)(ws + 33554432);           //  1 MB  head-major Wkv bf16
  u16* wqT = (u16*)(ws + 34603008);            // .5 MB  Wq^T bf16 [i][ch]
  u16* wc = (u16*)(ws + 35127296);             //  4 MB  Wc bf16 [b][o][ch]
  u16* weff = (u16*)(ws + 39321600);           //  4 MB  Weff bf16 [b][o][i]
  float* ctx = (float*)(ws + 43515904);        //  1 MB  [bh][d][e] fp32 (atomic)
  float* rsum = (float*)(ws + 44564480);       // 16 KB  [bh*64+d]   fp32 (atomic)

  pre<<<4932, 256, 0, stream>>>(x, xt, w_qkv, wkvh, wqT, ctx);
  kvctx<<<2048, 256, 0, stream>>>(wkvh, xt, ctx, rsum);
  wc_kern<<<dim3(64, 4), 256, 0, stream>>>(ctx, rsum, w_out, wc);
  weff_gemm<<<dim3(4, 4, 8), 256, 0, stream>>>(wc, wqT, weff);
  out_gemm<<<dim3(32, 4, 8), 256, 0, stream>>>(weff, xt, b_out, out);
}

// Round 10
// 242.005 us; speedup vs baseline: 1.3277x; 1.0485x over previous
//
#include <hip/hip_runtime.h>
#include <hip/hip_bf16.h>
#include <cstdint>

typedef unsigned short u16;
typedef __attribute__((ext_vector_type(8))) short bf16x8;
typedef __attribute__((ext_vector_type(4))) float f32x4;

__device__ __forceinline__ u16 f2b(float f) {
  union { float f; unsigned u; } x; x.f = f;
  unsigned r = x.u + 0x7fffu + ((x.u >> 16) & 1u);   // RNE
  return (u16)(r >> 16);
}
__device__ __forceinline__ float b2f(u16 u) {
  union { unsigned u; float f; } x; x.u = ((unsigned)u) << 16;
  return x.f;
}
__device__ __forceinline__ void gld16(void* lds, const void* g) {
  __builtin_amdgcn_global_load_lds((const __attribute__((address_space(1))) void*)g,
                                   (__attribute__((address_space(3))) void*)lds, 16, 0, 0);
}
__device__ __forceinline__ int sw_idx(int n, int c) {
  return n * 64 + ((((c >> 2) ^ (n >> 2)) & 15) << 2) + (c & 3);
}
// Ek/Vs swizzle: bijective per row; conflict-free for both the scalar b16
// epilogue writes and the 16B fragment reads.
__device__ __forceinline__ int ekb(int row, int c2) {
  return (row * 256 + c2) ^ ((((row >> 3) ^ row) & 7) << 4);
}

// ---------------------------------------------------------------------------
// pre: fused preprocessing (one launch).  (verified R6/R8)
//  blk<4096    : xt path — transpose-convert x [b][512][4096] fp32 ->
//                xt [b][4096][512] bf16 (64x64 tiles via swizzled LDS)
//  blk<4608    : convert w_qkv rows 512..1535 -> wkvh bf16, HEAD-MAJOR
//  blk<4672    : transpose-convert w_qkv rows 0..511 -> wqT bf16 [i][ch]
//  else        : zero ctx+rsum (266240 floats)
// ---------------------------------------------------------------------------
__global__ __launch_bounds__(256) void pre(const float* __restrict__ x,
                                           u16* __restrict__ xt,
                                           const float* __restrict__ w_qkv,
                                           u16* __restrict__ wkvh,
                                           u16* __restrict__ wqT,
                                           float* __restrict__ zbuf) {
  __shared__ u16 t[4096];
  const int tid = threadIdx.x;
  const int blk = blockIdx.x;
  if (blk < 4096) {
    const int b = blk >> 9;
    const int c0 = ((blk >> 6) & 7) * 64;
    const int n0 = (blk & 63) * 64;
    const int nl = (tid & 15) * 4;
    const int cl = tid >> 4;
#pragma unroll
    for (int r = 0; r < 4; r++) {
      const int c = cl + r * 16;
      const float4 v = *(const float4*)(x + ((long)b * 512 + c0 + c) * 4096 + n0 + nl);
      t[sw_idx(nl + 0, c)] = f2b(v.x);
      t[sw_idx(nl + 1, c)] = f2b(v.y);
      t[sw_idx(nl + 2, c)] = f2b(v.z);
      t[sw_idx(nl + 3, c)] = f2b(v.w);
    }
    __syncthreads();
    const int cw = (tid & 15) * 4;
#pragma unroll
    for (int r = 0; r < 4; r++) {
      const int n = cl + r * 16;
      const u16* tp = &t[sw_idx(n, cw)];
      ushort4 o; o.x = tp[0]; o.y = tp[1]; o.z = tp[2]; o.w = tp[3];
      *(ushort4*)(xt + ((long)b * 4096 + n0 + n) * 512 + c0 + cw) = o;
    }
    return;
  }
  const int pblk = blk - 4096;
  if (pblk < 512) {
    const int i = pblk * 1024 + tid * 4;
    const int ri = i >> 9;          // 0..1023 (0..511 = k, 512..1023 = v)
    const int col = i & 511;
    const int h = (ri >> 6) & 7;
    const int orow = h * 128 + ((ri >> 9) << 6) + (ri & 63);
    const float4 v = *(const float4*)(w_qkv + 262144 + i);
    ushort4 r; r.x = f2b(v.x); r.y = f2b(v.y); r.z = f2b(v.z); r.w = f2b(v.w);
    *(ushort4*)(wkvh + orow * 512 + col) = r;
  } else if (pblk < 576) {
    const int bb = pblk - 512;
    const int i0 = (bb & 7) * 64;
    const int c0 = (bb >> 3) * 64;
    const int il = (tid & 15) * 4;
    const int cl = tid >> 4;
#pragma unroll
    for (int r = 0; r < 4; r++) {
      const int c = cl + r * 16;
      const float4 v = *(const float4*)(w_qkv + (c0 + c) * 512 + i0 + il);
      t[sw_idx(il + 0, c)] = f2b(v.x);
      t[sw_idx(il + 1, c)] = f2b(v.y);
      t[sw_idx(il + 2, c)] = f2b(v.z);
      t[sw_idx(il + 3, c)] = f2b(v.w);
    }
    __syncthreads();
    const int cw = (tid & 15) * 4;
#pragma unroll
    for (int r = 0; r < 4; r++) {
      const int i = cl + r * 16;
      const u16* tp = &t[sw_idx(i, cw)];
      ushort4 o; o.x = tp[0]; o.y = tp[1]; o.z = tp[2]; o.w = tp[3];
      *(ushort4*)(wqT + (i0 + i) * 512 + c0 + cw) = o;
    }
  } else {
    const int zi = (pblk - 576) * 1024 + tid * 4;
    if (zi < 266240) *(float4*)(zbuf + zi) = float4{0.f, 0.f, 0.f, 0.f};
  }
}

// ---------------------------------------------------------------------------
// kvctx: fused kv_gemm + ctx_gemm. (verified R4/R8 — byte-identical)
// ---------------------------------------------------------------------------
__global__ __launch_bounds__(256, 4) void kvctx(const u16* __restrict__ wkvh,
                                                const u16* __restrict__ xt,
                                                float* __restrict__ ctx,
                                                float* __restrict__ rsum) {
  __shared__ u16 sh[16384];      // 32 KB total
  u16* As = sh;                  // [128][64] 16 KB   (GEMM1 phase)
  u16* Bs = sh + 8192;           // [128][64] 16 KB   (GEMM1 phase)
  u16* Ek = sh;                  // [64][128] 16 KB   (aliases As, ctx phase)
  u16* Vs = sh + 8192;           // [64][128] 16 KB   (aliases Bs, ctx phase)

  const int tid = threadIdx.x;
  const int wid = tid >> 6;
  const int lane = tid & 63;
  const int wm = wid >> 1, wn = wid & 1;

  // XCD-chunked work decode: 256 tiles (32 nc x 8 b), 8 heads each.
  const int flat = blockIdx.x;
  const int xcd = flat & 7;
  const int slot = flat >> 3;          // 0..255 per XCD
  const int h = slot & 7;
  const int tile = xcd * 32 + (slot >> 3);   // 0..255
  const int nc = tile & 31;
  const int b = tile >> 5;
  const int bh = b * 8 + h;

  const u16* Ab = wkvh + (long)h * 128 * 512;
  const u16* Bb = xt + ((long)b * 4096 + (long)nc * 128) * 512;
  const int q8 = (lane >> 4) * 8;
  const int mr = lane & 15;
  const int quad = lane >> 4;
  const int m7 = mr & 7;

  f32x4 acc[4][4] = {};

  // staging decode (per gld16 slot): row 0..127, chunk 0..7, swizzled source
  for (int kk = 0; kk < 512; kk += 64) {
    __syncthreads();
#pragma unroll
    for (int i = 0; i < 4; i++) {
      const int slot2 = i * 256 + tid;           // 0..1023
      const int row = slot2 >> 3;
      const int kc = ((slot2 & 7) ^ (row & 7)) * 8;   // pre-swizzled source
      gld16((char*)As + i * 4096 + wid * 1024, Ab + (long)row * 512 + kk + kc);
      gld16((char*)Bs + i * 4096 + wid * 1024, Bb + (long)row * 512 + kk + kc);
    }
    __syncthreads();
#pragma unroll
    for (int ks = 0; ks < 2; ks++) {
      bf16x8 af[4], bfv[4];
#pragma unroll
      for (int i = 0; i < 4; i++)
        af[i] = *(const bf16x8*)(As + (wm * 64 + i * 16 + mr) * 64 +
                                 (((ks * 4 + quad) ^ m7) * 8));
#pragma unroll
      for (int j = 0; j < 4; j++)
        bfv[j] = *(const bf16x8*)(Bs + (wn * 64 + j * 16 + mr) * 64 +
                                  (((ks * 4 + quad) ^ m7) * 8));
#pragma unroll
      for (int i = 0; i < 4; i++)
#pragma unroll
        for (int j = 0; j < 4; j++)
          acc[i][j] = __builtin_amdgcn_mfma_f32_16x16x32_bf16(af[i], bfv[j], acc[i][j], 0, 0, 0);
    }
  }

  // ---- epilogue: exp k-half, rsum, write swizzled LDS tiles ----
  __syncthreads();   // everyone done reading As/Bs before Ek overwrites them
  u16* dst = (wm == 0) ? Ek : Vs;   // wm=0 waves hold k rows 0..63, wm=1 v rows
#pragma unroll
  for (int i = 0; i < 4; i++) {
#pragma unroll
    for (int r = 0; r < 4; r++) {
      const int row = i * 16 + quad * 4 + r;   // 0..63 within half
      float sloc = 0.f;
#pragma unroll
      for (int j = 0; j < 4; j++) {
        float v = acc[i][j][r];
        if (wm == 0) v = __expf(v);
        const u16 bv = f2b(v);
        const int col = wn * 64 + j * 16 + mr;
        *(u16*)((char*)dst + ekb(row, col * 2)) = bv;
        if (wm == 0) sloc += b2f(bv);   // sum the rounded value for consistency
      }
      if (wm == 0) {
        sloc += __shfl_xor(sloc, 1);
        sloc += __shfl_xor(sloc, 2);
        sloc += __shfl_xor(sloc, 4);
        sloc += __shfl_xor(sloc, 8);
        if (mr == 0) atomicAdd(rsum + (long)bh * 64 + row, sloc);
      }
    }
  }
  __syncthreads();

  // ---- ctx MFMA: K = 128 n of this tile ----
  f32x4 acc2[2][2] = {};
#pragma unroll
  for (int ks = 0; ks < 4; ks++) {
    bf16x8 ef[2], vf[2];
#pragma unroll
    for (int ii = 0; ii < 2; ii++) {
      const int row = wm * 32 + ii * 16 + mr;          // d
      ef[ii] = *(const bf16x8*)((const char*)Ek + ekb(row, (ks * 32 + q8) * 2));
    }
#pragma unroll
    for (int jj = 0; jj < 2; jj++) {
      const int row = wn * 32 + jj * 16 + mr;          // e
      vf[jj] = *(const bf16x8*)((const char*)Vs + ekb(row, (ks * 32 + q8) * 2));
    }
#pragma unroll
    for (int ii = 0; ii < 2; ii++)
#pragma unroll
      for (int jj = 0; jj < 2; jj++)
        acc2[ii][jj] = __builtin_amdgcn_mfma_f32_16x16x32_bf16(ef[ii], vf[jj], acc2[ii][jj], 0, 0, 0);
  }

  // ---- ctx atomics ----
  float* cb = ctx + (long)bh * 4096;
#pragma unroll
  for (int ii = 0; ii < 2; ii++)
#pragma unroll
    for (int jj = 0; jj < 2; jj++)
#pragma unroll
      for (int r = 0; r < 4; r++) {
        const int d = wm * 32 + ii * 16 + quad * 4 + r;
        const int e = wn * 32 + jj * 16 + mr;
        atomicAdd(cb + d * 64 + e, acc2[ii][jj][r]);
      }
}

// ---------------------------------------------------------------------------
// Wc[b][o][h*64+d] = (sum_e w_out[o][h*64+e] * ctx[bh][d][e]) / rsum[bh*64+d]
// grid (64 bh, 16 og): 1024 blocks (was 256 — better fill); 8 o-rows/thread;
// reciprocal computed once per d (64 rcp in LDS) instead of 4096 divisions.
// ---------------------------------------------------------------------------
__global__ __launch_bounds__(256) void wc_kern(const float* __restrict__ ctxp,
                                               const float* __restrict__ rsump,
                                               const float* __restrict__ wout,
                                               u16* __restrict__ Wc) {
  __shared__ float cs[64 * 65];
  __shared__ float rinv[64];
  const int tid = threadIdx.x;
  const int bh = blockIdx.x, og = blockIdx.y;
  const int b = bh >> 3, h = bh & 7;
  if (tid < 64) rinv[tid] = 1.0f / rsump[(long)bh * 64 + tid];
  __syncthreads();
  for (int i = tid; i < 4096; i += 256) {
    const int d = i >> 6, e = i & 63;
    cs[e * 65 + d] = ctxp[(long)bh * 4096 + i] * rinv[d];
  }
  __syncthreads();
  const int d = tid & 63;
  const int o0 = og * 32 + (tid >> 6) * 8;
  float csr[64];
#pragma unroll
  for (int e = 0; e < 64; e++) csr[e] = cs[e * 65 + d];
  u16* wcp = Wc + (long)b * 512 * 512;
  for (int rr = 0; rr < 8; rr++) {
    const int o = o0 + rr;
    const float* wrow = wout + (long)o * 512 + h * 64;
    float a0 = 0.f, a1 = 0.f, a2 = 0.f, a3 = 0.f;
#pragma unroll
    for (int e = 0; e < 64; e += 4) {
      a0 += wrow[e + 0] * csr[e + 0];
      a1 += wrow[e + 1] * csr[e + 1];
      a2 += wrow[e + 2] * csr[e + 2];
      a3 += wrow[e + 3] * csr[e + 3];
    }
    wcp[(long)o * 512 + h * 64 + d] = f2b((a0 + a1) + (a2 + a3));
  }
}

// ---------------------------------------------------------------------------
// Weff[b][o][i] = 0.125 * sum_ch Wc[b][o][ch] * wqT[i][ch].
// 64x64 tiles, grid (8, 8, 8) = 512 blocks (was 128 = half-GPU idle).
// BK=64 + chunk-XOR swizzle (same verified scheme). Per-wave 32x32 out,
// acc[2][2] — fragment math identical to the 128^2 kernels.
// ---------------------------------------------------------------------------
__global__ __launch_bounds__(256) void weff_gemm(const u16* __restrict__ Wc,
                                                 const u16* __restrict__ wqT,
                                                 u16* __restrict__ Weff) {
  __shared__ u16 As[64 * 64];   // 8 KB
  __shared__ u16 Bs[64 * 64];   // 8 KB
  const int tid = threadIdx.x;
  const int wid = tid >> 6;
  const int lane = tid & 63;
  const int wm = wid >> 1, wn = wid & 1;
  const int gn = blockIdx.x, gm = blockIdx.y, b = blockIdx.z;

  const u16* Ab = Wc + (long)b * 512 * 512 + (long)gm * 64 * 512;
  const u16* Bb = wqT + (long)gn * 64 * 512;

  f32x4 acc[2][2] = {};
  const int mr = lane & 15;
  const int quad = lane >> 4;
  const int m7 = mr & 7;

  for (int kk = 0; kk < 512; kk += 64) {
    __syncthreads();
#pragma unroll
    for (int i = 0; i < 2; i++) {
      const int slot = i * 256 + tid;            // 0..511
      const int row = slot >> 3;                 // 0..63
      const int kc = ((slot & 7) ^ (row & 7)) * 8;
      gld16((char*)As + i * 4096 + wid * 1024, Ab + (long)row * 512 + kk + kc);
      gld16((char*)Bs + i * 4096 + wid * 1024, Bb + (long)row * 512 + kk + kc);
    }
    __syncthreads();
#pragma unroll
    for (int ks = 0; ks < 2; ks++) {
      bf16x8 af[2], bfv[2];
#pragma unroll
      for (int i = 0; i < 2; i++)
        af[i] = *(const bf16x8*)(As + (wm * 32 + i * 16 + mr) * 64 +
                                 (((ks * 4 + quad) ^ m7) * 8));
#pragma unroll
      for (int j = 0; j < 2; j++)
        bfv[j] = *(const bf16x8*)(Bs + (wn * 32 + j * 16 + mr) * 64 +
                                  (((ks * 4 + quad) ^ m7) * 8));
#pragma unroll
      for (int i = 0; i < 2; i++)
#pragma unroll
        for (int j = 0; j < 2; j++)
          acc[i][j] = __builtin_amdgcn_mfma_f32_16x16x32_bf16(af[i], bfv[j], acc[i][j], 0, 0, 0);
    }
  }

  const int col = lane & 15;
  u16* wb = Weff + (long)b * 512 * 512;
#pragma unroll
  for (int i = 0; i < 2; i++)
#pragma unroll
    for (int r = 0; r < 4; r++) {
      const int grow = gm * 64 + wm * 32 + i * 16 + quad * 4 + r;
#pragma unroll
      for (int j = 0; j < 2; j++) {
        const int gcol = gn * 64 + wn * 32 + j * 16 + col;
        wb[(long)grow * 512 + gcol] = f2b(acc[i][j][r] * 0.125f);
      }
    }
}

// ---------------------------------------------------------------------------
// out_gemm: out[b][o][n] = sum_i Weff[b][o][i] * xt[b][n][i] + bias[o]
// BK=64 + chunk-XOR swizzle (R4/R8-verified, byte-identical). grid (32,4,8).
// ---------------------------------------------------------------------------
__global__ __launch_bounds__(256) void out_gemm(const u16* __restrict__ Weff,
                                                const u16* __restrict__ xt,
                                                const float* __restrict__ bias,
                                                float* __restrict__ outp) {
  __shared__ u16 As[128 * 64];
  __shared__ u16 Bs[128 * 64];
  const int tid = threadIdx.x;
  const int wid = tid >> 6;
  const int lane = tid & 63;
  const int wm = wid >> 1, wn = wid & 1;
  const int gn = blockIdx.x, gm = blockIdx.y, b = blockIdx.z;

  const u16* Ab = Weff + (long)b * 512 * 512 + (long)gm * 128 * 512;
  const u16* Bb = xt + ((long)b * 4096 + (long)gn * 128) * 512;

  f32x4 acc[4][4] = {};
  const int mr = lane & 15;
  const int quad = lane >> 4;
  const int m7 = mr & 7;

  for (int kk = 0; kk < 512; kk += 64) {
    __syncthreads();
#pragma unroll
    for (int i = 0; i < 4; i++) {
      const int slot = i * 256 + tid;
      const int row = slot >> 3;
      const int kc = ((slot & 7) ^ (row & 7)) * 8;
      gld16((char*)As + i * 4096 + wid * 1024, Ab + (long)row * 512 + kk + kc);
      gld16((char*)Bs + i * 4096 + wid * 1024, Bb + (long)row * 512 + kk + kc);
    }
    __syncthreads();
#pragma unroll
    for (int ks = 0; ks < 2; ks++) {
      bf16x8 af[4], bfv[4];
#pragma unroll
      for (int i = 0; i < 4; i++)
        af[i] = *(const bf16x8*)(As + (wm * 64 + i * 16 + mr) * 64 +
                                 (((ks * 4 + quad) ^ m7) * 8));
#pragma unroll
      for (int j = 0; j < 4; j++)
        bfv[j] = *(const bf16x8*)(Bs + (wn * 64 + j * 16 + mr) * 64 +
                                  (((ks * 4 + quad) ^ m7) * 8));
#pragma unroll
      for (int i = 0; i < 4; i++)
#pragma unroll
        for (int j = 0; j < 4; j++)
          acc[i][j] = __builtin_amdgcn_mfma_f32_16x16x32_bf16(af[i], bfv[j], acc[i][j], 0, 0, 0);
    }
  }

  const int col = lane & 15;
#pragma unroll
  for (int i = 0; i < 4; i++)
#pragma unroll
    for (int r = 0; r < 4; r++) {
      const int grow = gm * 128 + wm * 64 + i * 16 + quad * 4 + r;
      const float bv = bias[grow];
#pragma unroll
      for (int j = 0; j < 4; j++) {
        const long gcol = (long)gn * 128 + wn * 64 + j * 16 + col;
        outp[((long)b * 512 + grow) * 4096 + gcol] = acc[i][j][r] + bv;
      }
    }
}

// ---------------------------------------------------------------------------
// launcher
// ---------------------------------------------------------------------------
extern "C" void kernel_launch(void* const* d_in, const int* in_sizes, int n_in,
                              void* d_out, int out_size, void* d_ws, size_t ws_size,
                              hipStream_t stream) {
  const float* x = (const float*)d_in[0];      // [8][512][4096]
  const float* w_qkv = (const float*)d_in[1];  // [1536][512]
  const float* w_out = (const float*)d_in[2];  // [512][512]
  const float* b_out = (const float*)d_in[3];  // [512]
  float* out = (float*)d_out;                  // [8][512][4096]
  char* ws = (char*)d_ws;

  u16* xt = (u16*)(ws + 0);                    // 32 MB  [b][n][512] bf16
  u16* wkvh = (u16*)(ws + 33554432);           //  1 MB  head-major Wkv bf16
  u16* wqT = (u16*)(ws + 34603008);            // .5 MB  Wq^T bf16 [i][ch]
  u16* wc = (u16*)(ws + 35127296);             //  4 MB  Wc bf16 [b][o][ch]
  u16* weff = (u16*)(ws + 39321600);           //  4 MB  Weff bf16 [b][o][i]
  float* ctx = (float*)(ws + 43515904);        //  1 MB  [bh][d][e] fp32 (atomic)
  float* rsum = (float*)(ws + 44564480);       // 16 KB  [bh*64+d]   fp32 (atomic)

  pre<<<4932, 256, 0, stream>>>(x, xt, w_qkv, wkvh, wqT, ctx);
  kvctx<<<2048, 256, 0, stream>>>(wkvh, xt, ctx, rsum);
  wc_kern<<<dim3(64, 16), 256, 0, stream>>>(ctx, rsum, w_out, wc);
  weff_gemm<<<dim3(8, 8, 8), 256, 0, stream>>>(wc, wqT, weff);
  out_gemm<<<dim3(32, 4, 8), 256, 0, stream>>>(weff, xt, b_out, out);
}